// Round 21
// baseline (185.171 us; speedup 1.0000x reference)
//
#include <hip/hip_runtime.h>
#include <hip/hip_bf16.h>
#include <stdint.h>

// ---------------------------------------------------------------------------
// MultiHeadAttention forward, MI355X bf16-MFMA implementation.
//   x[4,2048,1024] @ W_qkv[1024,3072] + b  -> Q,K -> [B,H,T,64], V -> [B,H,64,T]
//   flash attention per (b,h), T=2048, d=64 -> ctx [B,T,1024] bf16
//   ctx @ W_out + b_out -> out fp32 [4,2048,1024]
// Round 21 (isolation): r19-verified attn math (KVBLK=64, reg-staged
// dual-conflict-free XOR layout, canonical absmax 4.88e-4) with ONLY
// launch_bounds(512,4)->(512,2) from r20 (numerics-neutral: occupancy is
// grid-limited at 2 blocks/CU; looser VGPR cap removes spill pressure).
// Purpose: r20 (KVBLK=128) ran 184us but absmax rose to 1.32e-3 with no
// identifiable arithmetic difference — margin too thin to ship unexplained.
// This round splits the hypothesis: 4.88e-4 here => KVBLK=128 implicated.
// GEMMs (BK=64, r13) and prep (r9) unchanged.
// ---------------------------------------------------------------------------

typedef __attribute__((ext_vector_type(8))) short short8;
typedef __attribute__((ext_vector_type(4))) float f32x4;
typedef __attribute__((ext_vector_type(16))) float f32x16;
typedef __attribute__((ext_vector_type(4))) unsigned short ushort4_t;
typedef __attribute__((ext_vector_type(8))) unsigned short ushort8_t;

#define SEQ 2048
#define EDIM 1024
// 0.125 * log2(e): folded into Q so scores arrive in the log2 domain
#define QSCALE 0.18033688011112042f

__device__ __forceinline__ unsigned short f2bf(float x) {
  union { float f; uint32_t u; } v; v.f = x;
  uint32_t r = v.u + 0x7fffu + ((v.u >> 16) & 1u);
  return (unsigned short)(r >> 16);
}

__device__ __forceinline__ uint32_t cvtpk(float lo, float hi) {
  uint32_t r;
  asm("v_cvt_pk_bf16_f32 %0, %1, %2" : "=v"(r) : "v"(lo), "v"(hi));
  return r;
}

__device__ __forceinline__ float exp2_raw(float x) {
  float r;
  asm("v_exp_f32 %0, %1" : "=v"(r) : "v"(x));
  return r;
}

__device__ __forceinline__ void gload_lds16(const void* g, void* l) {
  typedef __attribute__((address_space(1))) const unsigned int gu32;
  typedef __attribute__((address_space(3))) unsigned int lu32;
  __builtin_amdgcn_global_load_lds((gu32*)g, (lu32*)l, 16, 0, 0);
}

// ------------------------- merged prep: fp32->bf16 cvt + 2 weight transposes
// grid 8192: [0,4096) cvt x; [4096,7168) Wqkv^T; [7168,8192) Wout^T
__global__ void k_prep(const float* __restrict__ x,
                       unsigned short* __restrict__ xb,
                       const float* __restrict__ Wq,
                       unsigned short* __restrict__ wqt,
                       const float* __restrict__ Wo,
                       unsigned short* __restrict__ wot) {
  __shared__ float tile[32][33];
  const int id = blockIdx.x;
  if (id < 4096) {
    const int i = id * 256 + threadIdx.x;      // exactly covers 1048576
    const float4* p = ((const float4*)x) + (size_t)i * 2;
    float4 a = p[0], b = p[1];
    ushort8_t v;
    v[0] = f2bf(a.x); v[1] = f2bf(a.y); v[2] = f2bf(a.z); v[3] = f2bf(a.w);
    v[4] = f2bf(b.x); v[5] = f2bf(b.y); v[6] = f2bf(b.z); v[7] = f2bf(b.w);
    ((ushort8_t*)xb)[i] = v;
    return;
  }
  const float* W;
  unsigned short* Wt;
  int N, bx, by;
  if (id < 7168) { W = Wq; Wt = wqt; N = 3072; bx = (id - 4096) % 96; by = (id - 4096) / 96; }
  else           { W = Wo; Wt = wot; N = 1024; bx = (id - 7168) % 32; by = (id - 7168) / 32; }
  const int K = 1024;
  const int c0 = bx * 32, r0 = by * 32;
  const int tx = threadIdx.x & 31, ty = threadIdx.x >> 5;
#pragma unroll
  for (int i = 0; i < 4; ++i) {
    int r = ty + i * 8;
    tile[r][tx] = W[(size_t)(r0 + r) * N + c0 + tx];
  }
  __syncthreads();
#pragma unroll
  for (int i = 0; i < 4; ++i) {
    int r = ty + i * 8;
    Wt[(size_t)(c0 + r) * K + r0 + tx] = f2bf(tile[tx][r]);
  }
}

// --------------------------------------------------------------- 128^2 GEMM
// A [M][1024] bf16, Bt [N][1024] bf16. EPI 0: QKV scatter (Q pre-scaled).
// EPI 1: fp32 out. XCD-aware swizzle (verified round 8). BK=64 via two
// 32-wide sub-steps per barrier pair (iterations 32 -> 16; verified round 13).
template <int EPI, int NBX>
__global__ __launch_bounds__(256, 2) void k_gemm(
    const unsigned short* __restrict__ A, const unsigned short* __restrict__ Bt,
    const float* __restrict__ bias, unsigned short* __restrict__ Qo,
    unsigned short* __restrict__ Ko, unsigned short* __restrict__ VTo,
    float* __restrict__ Out) {
  __shared__ unsigned short As[2][2][128 * 32];   // [buf][sub] 8 KB each
  __shared__ unsigned short Bs[2][2][128 * 32];
  const int tid = threadIdx.x;
  const int lane = tid & 63, wid = tid >> 6;
  const int wr = wid >> 1, wc = wid & 1;
  const int g = lane >> 4, r = lane & 15;
  const int lid = blockIdx.y * NBX + blockIdx.x;
  const int total = NBX * gridDim.y;
  const int id = (lid & 7) * (total >> 3) + (lid >> 3);
  const int m0 = (id / NBX) * 128, n0 = (id % NBX) * 128;

  // hoisted staging pointers: seg i*256+tid -> row=seg>>2, sl=seg&3
  const int row0 = tid >> 2, sl0 = tid & 3;        // i=0: rows 0..63
  const unsigned short* a0 = A + (size_t)(m0 + row0) * 1024 + sl0 * 8;
  const unsigned short* a1 = A + (size_t)(m0 + 64 + row0) * 1024 + sl0 * 8;
  const unsigned short* b0 = Bt + (size_t)(n0 + row0) * 1024 + sl0 * 8;
  const unsigned short* b1 = Bt + (size_t)(n0 + 64 + row0) * 1024 + sl0 * 8;
  char* adst = (char*)As + wid * 64 * 16;   // +4096 rows-half, +8192 sub, +16384 buf
  char* bdst = (char*)Bs + wid * 64 * 16;

  auto STAGE = [&](int buf) {  // stages one BK=64 K-step (both subs); advances
    const int bo = buf * 16384;
    gload_lds16(a0,      adst + bo);
    gload_lds16(a1,      adst + bo + 4096);
    gload_lds16(a0 + 32, adst + bo + 8192);
    gload_lds16(a1 + 32, adst + bo + 8192 + 4096);
    gload_lds16(b0,      bdst + bo);
    gload_lds16(b1,      bdst + bo + 4096);
    gload_lds16(b0 + 32, bdst + bo + 8192);
    gload_lds16(b1 + 32, bdst + bo + 8192 + 4096);
    a0 += 64; a1 += 64; b0 += 64; b1 += 64;
  };

  f32x4 zero4 = {0.f, 0.f, 0.f, 0.f};
  f32x4 acc[4][4];
#pragma unroll
  for (int mi = 0; mi < 4; ++mi)
#pragma unroll
    for (int ni = 0; ni < 4; ++ni) acc[mi][ni] = zero4;

  STAGE(0);
  asm volatile("s_waitcnt vmcnt(0)" ::: "memory");
  __builtin_amdgcn_s_barrier();

  for (int t = 0; t < 16; ++t) {
    const int cur = t & 1;
    if (t < 15) STAGE(cur ^ 1);        // issue next K-step's loads early
#pragma unroll
    for (int sub = 0; sub < 2; ++sub) {
      short8 af[4], bf[4];
#pragma unroll
      for (int mi = 0; mi < 4; ++mi)
        af[mi] = *(const short8*)&As[cur][sub][(wr * 64 + mi * 16 + r) * 32 + g * 8];
#pragma unroll
      for (int ni = 0; ni < 4; ++ni)
        bf[ni] = *(const short8*)&Bs[cur][sub][(wc * 64 + ni * 16 + r) * 32 + g * 8];
#pragma unroll
      for (int mi = 0; mi < 4; ++mi)
#pragma unroll
        for (int ni = 0; ni < 4; ++ni)
          acc[mi][ni] = __builtin_amdgcn_mfma_f32_16x16x32_bf16(
              af[mi], bf[ni], acc[mi][ni], 0, 0, 0);
    }
    asm volatile("s_waitcnt vmcnt(0)" ::: "memory");  // next-step loads landed
    __builtin_amdgcn_s_barrier();
  }

#pragma unroll
  for (int mi = 0; mi < 4; ++mi) {
#pragma unroll
    for (int ni = 0; ni < 4; ++ni) {
      const int n = n0 + wc * 64 + ni * 16 + r;
      const float bv = bias[n];
      const int mbase = m0 + wr * 64 + mi * 16 + g * 4;
      if (EPI == 0) {
        const int sec = n >> 10, e = n & 1023, h = e >> 6, dd = e & 63;
        const int b = mbase >> 11, t = mbase & 2047;
        if (sec == 2) {  // V transposed: [B,H,64,2048], 4 consecutive t packed
          ushort4_t pk;
#pragma unroll
          for (int j = 0; j < 4; ++j) pk[j] = f2bf(acc[mi][ni][j] + bv);
          *(ushort4_t*)&VTo[(((size_t)b * 16 + h) * 64 + dd) * 2048 + t] = pk;
        } else {
          unsigned short* dst = (sec == 0) ? Qo : Ko;
          const float scl = (sec == 0) ? QSCALE : 1.0f;  // fold softmax scale
#pragma unroll
          for (int j = 0; j < 4; ++j)
            dst[(((size_t)b * 16 + h) * 2048 + t + j) * 64 + dd] =
                f2bf((acc[mi][ni][j] + bv) * scl);
        }
      } else {
#pragma unroll
        for (int j = 0; j < 4; ++j)
          Out[(size_t)(mbase + j) * 1024 + n] = acc[mi][ni][j] + bv;
      }
    }
  }
}

// ------------------------------------------------------------ flash attention
// 1D grid 512, XCD-swizzled. 8 waves; wave owns 32 q-rows x ALL 64 keys.
// KV tile 64, double-buffered. REG-STAGED (coalesced rows) -> ds_write to
// dual-conflict-free XOR layout right after QK^T -> lane-cyclic conflict-free
// fragment reads. launch_bounds(512,2): occupancy grid-limited at 2 blocks/CU,
// so the 128-VGPR budget is free (no spill pressure). r19-verified math.
// Basis-free softmax; all-ones-MFMA row-sum.
__global__ __launch_bounds__(512, 2) void k_attn(
    const unsigned short* __restrict__ Qg, const unsigned short* __restrict__ Kg,
    const unsigned short* __restrict__ VTg, const int* __restrict__ maskp,
    unsigned short* __restrict__ ctx) {
  __shared__ unsigned short Ks[2 * 4096];     // [buf][512 slots x 16B]
  __shared__ unsigned short Vs[2 * 4096];
  const int tid = threadIdx.x, lane = tid & 63, wid = tid >> 6;
  const int q = lane & 31, hi = lane >> 5;
  const int id = blockIdx.x;
  const int slot = id >> 3;
  const int bh = (id & 7) * 8 + (slot >> 3);
  const int b = bh >> 4, h = bh & 15;
  const int q0 = (slot & 7) * 256 + wid * 32;
  const int qr = q0 + q;

  const unsigned short* Qb = Qg + (size_t)bh * SEQ * 64;
  const unsigned short* Kb = Kg + (size_t)bh * SEQ * 64;
  const unsigned short* Vb = VTg + (size_t)bh * 64 * SEQ;
  const int* mb = maskp + b * SEQ;

  // reg-staging geometry: thread t -> row t>>3, chunk c=t&7 (coalesced rows)
  const int srow = tid >> 3, sc = tid & 7;
  const unsigned short* kp = Kb + srow * 64 + sc * 8;            // +4096/tile
  const unsigned short* vp = Vb + (size_t)srow * SEQ + sc * 8;   // +64/tile
  // phys slot = [(c>>1)*128 + (row>>5)*64 + (c&1)*32 + (row&31)] ^ (c&7)
  const int pslot = ((sc >> 1) * 128 + (srow >> 5) * 64 + (sc & 1) * 32 +
                     (srow & 31)) ^ (sc & 7);
  char* kw = (char*)Ks + pslot * 16;          // + buf*8192
  char* vw = (char*)Vs + pslot * 16;

  // Q fragments (B-operand of S^T mfma): lane holds Q[qr][ds*16 + hi*8 + 0..7]
  short8 qf[4];
#pragma unroll
  for (int ds = 0; ds < 4; ++ds)
    qf[ds] = *(const short8*)&Qb[(size_t)qr * 64 + ds * 16 + hi * 8];

  // all-ones bf16 A-fragment (constant matrix => fragment-layout-proof)
  short8 onesf;
#pragma unroll
  for (int j = 0; j < 8; ++j) onesf[j] = (short)0x3F80;

  f32x16 z16 = {0.f,0.f,0.f,0.f,0.f,0.f,0.f,0.f,0.f,0.f,0.f,0.f,0.f,0.f,0.f,0.f};
  f32x16 o0 = z16, o1 = z16;   // O^T[dd][q]: dd = (i&3)+8*(i>>2)+4*hi (+32)
  f32x16 osum = z16;           // every component = sum_k P[q][k] (all rows =)
  const int kb4 = hi * 4;

  // prologue: stage tile 0 through registers into buf 0
  {
    short8 kreg = *(const short8*)kp;  kp += 4096;
    short8 vreg = *(const short8*)vp;  vp += 64;
    *(short8*)kw = kreg;
    *(short8*)vw = vreg;
  }
  const int* mptr = mb + lane;
  int mv = mptr[0];
  mptr += 64;
  __syncthreads();

  for (int t = 0; t < 32; ++t) {
    const int cur = t & 1;
    // unconditional loads of tile t+1 (t=31 reloads tile 31 -> discarded)
    short8 kreg = *(const short8*)kp;
    short8 vreg = *(const short8*)vp;
    const int mvn = mptr[0];
    if (t < 30) { kp += 4096; vp += 64; mptr += 64; }
    const unsigned long long bits = __ballot(mv != 0);
    mv = mvn;

    // S^T = K Q^T : lane holds S^T[key][q=lane&31], keys (i&3)+8*(i>>2)+4*hi
    const char* KsB = (const char*)Ks + cur * 8192;
    const char* VsB = (const char*)Vs + cur * 8192;
    f32x16 c0 = z16, c1 = z16;
    __builtin_amdgcn_s_setprio(1);
#pragma unroll
    for (int ds = 0; ds < 4; ++ds) {
      const int ko = (lane ^ ((ds * 2 + hi) & 7)) * 16 + ds * 2048;
      short8 ka0 = *(const short8*)(KsB + ko);
      short8 ka1 = *(const short8*)(KsB + ko + 1024);
      c0 = __builtin_amdgcn_mfma_f32_32x32x16_bf16(ka0, qf[ds], c0, 0, 0, 0);
      c1 = __builtin_amdgcn_mfma_f32_32x32x16_bf16(ka1, qf[ds], c1, 0, 0, 0);
    }
    __builtin_amdgcn_s_setprio(0);

    // write tile t+1 into buf cur^1 NOW (short kreg/vreg live range; QK^T
    // above hid the L2 latency; barrier-separated from all cur^1 readers)
    {
      const int bo = (cur ^ 1) * 8192;
      *(short8*)(kw + bo) = kreg;
      *(short8*)(vw + bo) = vreg;
    }

    // P = exp2(S') directly — scale folded into Q, basis-free (cancels)
#pragma unroll
    for (int i = 0; i < 16; ++i) {
      c0[i] = exp2_raw(c0[i]);
      c1[i] = exp2_raw(c1[i]);
    }
    if (bits != ~0ull) {  // wave-uniform: only when mask has zeros
#pragma unroll
      for (int i = 0; i < 16; ++i) {
        const int k0 = (i & 3) + 8 * (i >> 2) + kb4;
        if (!((bits >> k0) & 1)) c0[i] = 0.f;
        if (!((bits >> (k0 + 32)) & 1)) c1[i] = 0.f;
      }
    }

    // P -> bf16 PV fragments, in-register (cvt_pk + permlane32_swap)
    short8 pf[4];
#pragma unroll
    for (int sub = 0; sub < 2; ++sub) {
      uint32_t w[8];
#pragma unroll
      for (int j = 0; j < 8; ++j)
        w[j] = sub ? cvtpk(c1[2 * j], c1[2 * j + 1])
                   : cvtpk(c0[2 * j], c0[2 * j + 1]);
      asm("v_permlane32_swap_b32 %0, %1" : "+v"(w[0]), "+v"(w[2]));
      asm("v_permlane32_swap_b32 %0, %1" : "+v"(w[1]), "+v"(w[3]));
      asm("v_permlane32_swap_b32 %0, %1" : "+v"(w[4]), "+v"(w[6]));
      asm("v_permlane32_swap_b32 %0, %1" : "+v"(w[5]), "+v"(w[7]));
      union { uint32_t u[4]; short8 s; } ua, ub;
      ua.u[0] = w[0]; ua.u[1] = w[1]; ua.u[2] = w[2]; ua.u[3] = w[3];
      ub.u[0] = w[4]; ub.u[1] = w[5]; ub.u[2] = w[6]; ub.u[3] = w[7];
      pf[sub * 2] = ua.s;
      pf[sub * 2 + 1] = ub.s;
    }

    // O^T += V^T P^T ; row-sum += 1 * P^T (all-ones A => each row = sum_k P)
    __builtin_amdgcn_s_setprio(1);
#pragma unroll
    for (int ks = 0; ks < 4; ++ks) {
      const int vo = (lane ^ ((ks * 2 + hi) & 7)) * 16 + ks * 2048;
      short8 va0 = *(const short8*)(VsB + vo);
      short8 va1 = *(const short8*)(VsB + vo + 1024);
      o0 = __builtin_amdgcn_mfma_f32_32x32x16_bf16(va0, pf[ks], o0, 0, 0, 0);
      o1 = __builtin_amdgcn_mfma_f32_32x32x16_bf16(va1, pf[ks], o1, 0, 0, 0);
      osum = __builtin_amdgcn_mfma_f32_32x32x16_bf16(onesf, pf[ks], osum,
                                                     0, 0, 0);
    }
    __builtin_amdgcn_s_setprio(0);

    __syncthreads();
  }

  // ctx [B,T,1024] bf16: lane writes its query row qr, dd groups of 4
  const float inv = 1.f / osum[0];
#pragma unroll
  for (int ns = 0; ns < 2; ++ns) {
#pragma unroll
    for (int g_ = 0; g_ < 4; ++g_) {
      ushort4_t v4;
#pragma unroll
      for (int e = 0; e < 4; ++e) {
        const float val = (ns ? o1[g_ * 4 + e] : o0[g_ * 4 + e]) * inv;
        v4[e] = f2bf(val);
      }
      *(ushort4_t*)&ctx[((size_t)b * SEQ + qr) * 1024 + h * 64 + ns * 32 +
                        g_ * 8 + hi * 4] = v4;
    }
  }
}

// ---------------------------------------------------------------------------
extern "C" void kernel_launch(void* const* d_in, const int* in_sizes, int n_in,
                              void* d_out, int out_size, void* d_ws,
                              size_t ws_size, hipStream_t stream) {
  const float* x = (const float*)d_in[0];
  const int* mask = (const int*)d_in[1];
  const float* Wqkv = (const float*)d_in[2];
  const float* bqkv = (const float*)d_in[3];
  const float* Wout = (const float*)d_in[4];
  const float* bout = (const float*)d_in[5];
  float* out = (float*)d_out;

  unsigned short* ws = (unsigned short*)d_ws;
  unsigned short* xb = ws;                       // 8388608 (reused as ctx)
  unsigned short* wqt = ws + 8388608;            // 3145728
  unsigned short* wot = ws + 11534336;           // 1048576
  unsigned short* Q = ws + 12582912;             // 8388608
  unsigned short* K = ws + 20971520;             // 8388608
  unsigned short* VT = ws + 29360128;            // 8388608
  unsigned short* ctx = xb;

  k_prep<<<8192, 256, 0, stream>>>(x, xb, Wqkv, wqt, Wout, wot);
  k_gemm<0, 24><<<dim3(24, 64), 256, 0, stream>>>(xb, wqt, bqkv, Q, K, VT,
                                                  nullptr);
  k_attn<<<512, 512, 0, stream>>>(Q, K, VT, mask, ctx);
  k_gemm<1, 8><<<dim3(8, 64), 256, 0, stream>>>(ctx, wot, bout, nullptr,
                                                nullptr, nullptr, out);
}